// Round 2
// baseline (2665.119 us; speedup 1.0000x reference)
//
#include <hip/hip_runtime.h>

#define NB 32
#define NT 120
#define NG 25
#define ND 256
#define NH 8
#define NHD 32

typedef unsigned short u16;
typedef unsigned int u32;

__device__ __forceinline__ float bf2f(u16 u) { return __uint_as_float(((u32)u) << 16); }
__device__ __forceinline__ float bflo(u32 u) { return __uint_as_float(u << 16); }
__device__ __forceinline__ float bfhi(u32 u) { return __uint_as_float(u & 0xFFFF0000u); }
__device__ __forceinline__ u16 f2bf(float f) {   // round-to-nearest-even
    u32 x = __float_as_uint(f);
    return (u16)((x + 0x7FFFu + ((x >> 16) & 1u)) >> 16);
}

// dtype-generic scalar load
template<bool F32>
__device__ __forceinline__ float ldg1(const void* p, long i) {
    if constexpr (F32) return ((const float*)p)[i];
    else               return bf2f(((const u16*)p)[i]);
}
// dtype-generic 8-wide load (i must be a multiple of 8)
template<bool F32>
__device__ __forceinline__ void ld8(const void* p, long i, float o[8]) {
    if constexpr (F32) {
        const float4* q = (const float4*)((const float*)p + i);
        float4 a = q[0], b = q[1];
        o[0]=a.x; o[1]=a.y; o[2]=a.z; o[3]=a.w;
        o[4]=b.x; o[5]=b.y; o[6]=b.z; o[7]=b.w;
    } else {
        uint4 w = *(const uint4*)((const u16*)p + i);
        o[0]=bflo(w.x); o[1]=bfhi(w.x); o[2]=bflo(w.y); o[3]=bfhi(w.y);
        o[4]=bflo(w.z); o[5]=bfhi(w.z); o[6]=bflo(w.w); o[7]=bfhi(w.w);
    }
}

// Decide wire dtype from the adjacency matrix (values ~ uniform[0,1)).
// As bf16: every u16 has sign=0 and exponent field <= 0x7F.
// As f32: low halves are ~random u16s -> certain detection over 625 words.
__global__ __launch_bounds__(256) void detect_dtype(const u16* adj, int* flag) {
    __shared__ int s;
    if (threadIdx.x == 0) s = 0;
    __syncthreads();
    int local = 0;
    for (int i = threadIdx.x; i < NG * NG; i += 256) {
        u16 v = adj[i];
        if (v >= 0x8000u || ((v >> 7) & 0xFFu) >= 0x82u) local = 1;
    }
    if (local) atomicOr(&s, 1);
    __syncthreads();
    if (threadIdx.x == 0) *flag = s;   // 1 => inputs are float32
}

// Block-wide stats for 25 independent rows: thread d holds zv[g] = row g, col d.
__device__ __forceinline__ void norm_stats(const float (&zv)[NG], int lane, int wid, int d,
                                           float (*s_wred)[NG][2], float* s_mu, float* s_rsd) {
    #pragma unroll
    for (int g = 0; g < NG; ++g) {
        float s = zv[g], q = zv[g] * zv[g];
        #pragma unroll
        for (int off = 32; off > 0; off >>= 1) {
            s += __shfl_xor(s, off, 64);
            q += __shfl_xor(q, off, 64);
        }
        if (lane == 0) { s_wred[wid][g][0] = s; s_wred[wid][g][1] = q; }
    }
    __syncthreads();
    if (d < NG) {
        float s = 0.f, q = 0.f;
        #pragma unroll
        for (int w = 0; w < 4; ++w) { s += s_wred[w][d][0]; q += s_wred[w][d][1]; }
        float mu = s * (1.f / 256.f);
        float var = fmaxf((q - 256.f * mu * mu) * (1.f / 255.f), 0.f);  // ddof=1
        s_mu[d] = mu;
        s_rsd[d] = 1.f / (sqrtf(var) + 1e-6f);   // torch: alpha*(z-mu)/(std+eps)+beta
    }
    __syncthreads();
}

template<bool F32>
__global__ __launch_bounds__(256)
void enc_fused(const void* __restrict__ x,  const void* __restrict__ adj,
               const void* __restrict__ Wq, const void* __restrict__ bq,
               const void* __restrict__ Wk, const void* __restrict__ bk,
               const void* __restrict__ Wv, const void* __restrict__ bv,
               const void* __restrict__ Wo, const void* __restrict__ bo,
               const void* __restrict__ Wfc,const void* __restrict__ bfc,
               const void* __restrict__ alpha, const void* __restrict__ beta,
               void* __restrict__ out, const int* __restrict__ flag)
{
    if ((flag[0] != 0) != F32) return;   // wrong-dtype variant: exit before any barrier

    // LDS region plan (phase-overlapped), 64000 B main + 1000 B scratch:
    //  [0,25600)      hs (f32) P1-P2 -> ss (f32, 6400B) P3-P5 -> zs/x1 (f32) P7-P8
    //  [25600,38400)  Qs (bf16) P2-P3 -> atts (bf16) P5-P6
    //  [38400,51200)  adjf (f32, 2500B) P0-P1 -> Ks (bf16) P2-P3
    //  [51200,64000)  Vs (bf16) P2-P5
    __shared__ __align__(16) char sm[64000];
    __shared__ float s_mu[NG], s_rsd[NG];
    __shared__ float s_wred[4][NG][2];

    float* hs   = (float*)sm;
    float* ss   = (float*)sm;
    float* zs   = (float*)sm;
    u16*   Qs   = (u16*)(sm + 25600);
    u16*   atts = (u16*)(sm + 25600);
    float* adjf = (float*)(sm + 38400);
    u16*   Ks   = (u16*)(sm + 38400);
    u16*   Vs   = (u16*)(sm + 51200);

    const int bt = blockIdx.x;
    const int d = threadIdx.x;
    const int lane = d & 63, wid = d >> 6;
    const long base = (long)bt * (NG * ND);

    // ---- P0: stage adjacency (f32) ----
    for (int i = d; i < NG * NG; i += ND)
        adjf[i] = ldg1<F32>(adj, i);
    __syncthreads();

    // ---- P1: h[g][d] = sum_n adj[g,n] * x[n][d]  (x straight from global) ----
    {
        float acc[NG];
        #pragma unroll
        for (int g = 0; g < NG; ++g) acc[g] = 0.f;
        for (int n = 0; n < NG; ++n) {
            float xv = ldg1<F32>(x, base + n * ND + d);
            #pragma unroll
            for (int g = 0; g < NG; ++g) acc[g] += adjf[g * NG + n] * xv;
        }
        #pragma unroll
        for (int g = 0; g < NG; ++g) hs[g * ND + d] = acc[g];
    }
    __syncthreads();   // adjf dead after this; hs visible

    // ---- P2: Q,K,V = h @ W^T + b (bf16 into LDS) ----
    {
        float aq[NG], ak[NG], av[NG];
        const float bqd = ldg1<F32>(bq, d), bkd = ldg1<F32>(bk, d), bvd = ldg1<F32>(bv, d);
        #pragma unroll
        for (int g = 0; g < NG; ++g) { aq[g] = bqd; ak[g] = bkd; av[g] = bvd; }
        const long wrow = (long)d * ND;
        for (int k = 0; k < ND; k += 8) {
            float qf[8], kf[8], vf[8];
            ld8<F32>(Wq, wrow + k, qf);
            ld8<F32>(Wk, wrow + k, kf);
            ld8<F32>(Wv, wrow + k, vf);
            #pragma unroll
            for (int g = 0; g < NG; ++g) {
                const float* hrow = hs + g * ND + k;
                const float4 h0 = *(const float4*)(hrow);
                const float4 h1 = *(const float4*)(hrow + 4);
                aq[g] += h0.x*qf[0] + h0.y*qf[1] + h0.z*qf[2] + h0.w*qf[3]
                       + h1.x*qf[4] + h1.y*qf[5] + h1.z*qf[6] + h1.w*qf[7];
                ak[g] += h0.x*kf[0] + h0.y*kf[1] + h0.z*kf[2] + h0.w*kf[3]
                       + h1.x*kf[4] + h1.y*kf[5] + h1.z*kf[6] + h1.w*kf[7];
                av[g] += h0.x*vf[0] + h0.y*vf[1] + h0.z*vf[2] + h0.w*vf[3]
                       + h1.x*vf[4] + h1.y*vf[5] + h1.z*vf[6] + h1.w*vf[7];
            }
        }
        #pragma unroll
        for (int g = 0; g < NG; ++g) {
            Qs[g * ND + d] = f2bf(aq[g]);
            Ks[g * ND + d] = f2bf(ak[g]);
            Vs[g * ND + d] = f2bf(av[g]);
        }
    }
    __syncthreads();   // hs dead after this

    // ---- P3: scores[g][h1][h2] = (Q_g K_g^T)/sqrt(32) ----
    for (int i = d; i < NG * 64; i += ND) {
        const int g = i >> 6, hh = i & 63;
        const u16* qrow = Qs + g * ND + (hh >> 3) * NHD;
        const u16* krow = Ks + g * ND + (hh & 7) * NHD;
        float s = 0.f;
        #pragma unroll
        for (int hd = 0; hd < NHD; hd += 4) {
            ushort4 qa = *(const ushort4*)(qrow + hd);
            ushort4 ka = *(const ushort4*)(krow + hd);
            s += bf2f(qa.x)*bf2f(ka.x) + bf2f(qa.y)*bf2f(ka.y)
               + bf2f(qa.z)*bf2f(ka.z) + bf2f(qa.w)*bf2f(ka.w);
        }
        ss[i] = s * 0.17677669529663687f;   // 1/sqrt(32)
    }
    __syncthreads();   // Qs,Ks dead after this

    // ---- P4: softmax over g (torch F.softmax on 5-D -> dim=1 = G axis) ----
    if (d < 64) {
        float m = -1e30f;
        for (int g = 0; g < NG; ++g) m = fmaxf(m, ss[g * 64 + d]);
        float den = 0.f;
        for (int g = 0; g < NG; ++g) den += expf(ss[g * 64 + d] - m);
        const float inv = 1.f / den;
        for (int g = 0; g < NG; ++g) ss[g * 64 + d] = expf(ss[g * 64 + d] - m) * inv;
    }
    __syncthreads();

    // ---- P5: att[g][h1*32+hd] = sum_h2 w[g][h1][h2] * V[g][h2*32+hd] ----
    {
        const int h1 = d >> 5, hd = d & 31;
        #pragma unroll
        for (int g = 0; g < NG; ++g) {
            float a = 0.f;
            #pragma unroll
            for (int h2 = 0; h2 < NH; ++h2)
                a += ss[g * 64 + h1 * 8 + h2] * bf2f(Vs[g * ND + h2 * NHD + hd]);
            atts[g * ND + d] = f2bf(a);
        }
    }
    __syncthreads();   // ss, Vs dead after this

    // ---- P6: z = x + att @ Wo^T + bo  (regs) ----
    float zv[NG];
    {
        const float bod = ldg1<F32>(bo, d);
        float acc[NG];
        #pragma unroll
        for (int g = 0; g < NG; ++g) acc[g] = bod;
        const long wrow = (long)d * ND;
        for (int k = 0; k < ND; k += 8) {
            float wf[8];
            ld8<F32>(Wo, wrow + k, wf);
            #pragma unroll
            for (int g = 0; g < NG; ++g) {
                uint4 aa = *(const uint4*)(atts + g * ND + k);
                acc[g] += bflo(aa.x)*wf[0] + bfhi(aa.x)*wf[1] + bflo(aa.y)*wf[2] + bfhi(aa.y)*wf[3]
                        + bflo(aa.z)*wf[4] + bfhi(aa.z)*wf[5] + bflo(aa.w)*wf[6] + bfhi(aa.w)*wf[7];
            }
        }
        #pragma unroll
        for (int g = 0; g < NG; ++g) zv[g] = ldg1<F32>(x, base + g * ND + d) + acc[g];
    }

    // ---- P7: norm1 -> x1 (regs + f32 LDS for the FC matmul) ----
    norm_stats(zv, lane, wid, d, s_wred, s_mu, s_rsd);
    const float af = ldg1<F32>(alpha, d), bef = ldg1<F32>(beta, d);
    #pragma unroll
    for (int g = 0; g < NG; ++g) {
        const float x1 = af * (zv[g] - s_mu[g]) * s_rsd[g] + bef;
        zv[g] = x1;
        zs[g * ND + d] = x1;
    }
    __syncthreads();

    // ---- P8: z2 = x1 + relu(x1 @ Wfc^T + bfc) ----
    float z2[NG];
    {
        const float bfd = ldg1<F32>(bfc, d);
        float acc[NG];
        #pragma unroll
        for (int g = 0; g < NG; ++g) acc[g] = bfd;
        const long wrow = (long)d * ND;
        for (int k = 0; k < ND; k += 8) {
            float wf[8];
            ld8<F32>(Wfc, wrow + k, wf);
            #pragma unroll
            for (int g = 0; g < NG; ++g) {
                const float* xr = zs + g * ND + k;
                const float4 x0 = *(const float4*)(xr);
                const float4 x1v = *(const float4*)(xr + 4);
                acc[g] += x0.x*wf[0] + x0.y*wf[1] + x0.z*wf[2] + x0.w*wf[3]
                        + x1v.x*wf[4] + x1v.y*wf[5] + x1v.z*wf[6] + x1v.w*wf[7];
            }
        }
        #pragma unroll
        for (int g = 0; g < NG; ++g) z2[g] = zv[g] + fmaxf(acc[g], 0.f);
    }

    // ---- P9: norm2 -> output ----
    norm_stats(z2, lane, wid, d, s_wred, s_mu, s_rsd);
    #pragma unroll
    for (int g = 0; g < NG; ++g) {
        const float v = af * (z2[g] - s_mu[g]) * s_rsd[g] + bef;
        if constexpr (F32) ((float*)out)[base + g * ND + d] = v;
        else               ((u16*)out)[base + g * ND + d] = f2bf(v);
    }
}

extern "C" void kernel_launch(void* const* d_in, const int* in_sizes, int n_in,
                              void* d_out, int out_size, void* d_ws, size_t ws_size,
                              hipStream_t stream) {
    (void)in_sizes; (void)n_in; (void)ws_size; (void)out_size;
    const void* x     = d_in[0];
    const void* adj   = d_in[1];
    const void* Wq    = d_in[2];
    const void* bq    = d_in[3];
    const void* Wk    = d_in[4];
    const void* bk    = d_in[5];
    const void* Wv    = d_in[6];
    const void* bv    = d_in[7];
    const void* Wo    = d_in[8];
    const void* bo    = d_in[9];
    const void* Wfc   = d_in[10];
    const void* bfc   = d_in[11];
    const void* alpha = d_in[12];
    const void* beta  = d_in[13];
    int* flag = (int*)d_ws;

    detect_dtype<<<dim3(1), dim3(256), 0, stream>>>((const u16*)adj, flag);
    enc_fused<true ><<<dim3(NB * NT), dim3(256), 0, stream>>>(
        x, adj, Wq, bq, Wk, bk, Wv, bv, Wo, bo, Wfc, bfc, alpha, beta, d_out, flag);
    enc_fused<false><<<dim3(NB * NT), dim3(256), 0, stream>>>(
        x, adj, Wq, bq, Wk, bk, Wv, bv, Wo, bo, Wfc, bfc, alpha, beta, d_out, flag);
}

// Round 3
// 1222.146 us; speedup vs baseline: 2.1807x; 2.1807x over previous
//
#include <hip/hip_runtime.h>

#define NB 32
#define NT 120
#define NG 25
#define ND 256
#define NH 8
#define NHD 32

typedef unsigned short u16;
typedef unsigned int u32;

typedef __bf16 bf16x8 __attribute__((ext_vector_type(8)));
typedef float  f32x4  __attribute__((ext_vector_type(4)));

// ---- LDS layout (dynamic, 146640 B) ----
#define SB 264                    // bf16 row stride (elements)
#define SF 268                    // f32 row stride (elements)
#define OFF_HS_HI 0               // u16[32*264] = 16896
#define OFF_HS_LO 16896
#define OFF_QKV   33792           // f32[3][32][268] = 102912
#define OFF_ADJ   136704          // f32[625] (pad 2512)
#define OFF_SS    139216          // f32[1600] = 6400
#define OFF_WRED  145616          // f32[4][25][2] = 800
#define OFF_MU    146416          // f32[25] (pad 112)
#define OFF_RSD   146528          // f32[25] (pad 112)
#define SMEM_TOT  146640

// ---- ws split-weight plane offsets (u16 elements) ----
#define WS_QKV_HI 0
#define WS_QKV_LO 196608
#define WS_WO_HI  393216
#define WS_WO_LO  458752
#define WS_WFC_HI 524288
#define WS_WFC_LO 589824
#define WS_NEED_BYTES (655360ull * 2ull)   // 1,310,720 B

__device__ __forceinline__ float bf2f(u16 u) { return __uint_as_float(((u32)u) << 16); }
__device__ __forceinline__ u16 f2bf(float f) {   // round-to-nearest-even
    u32 x = __float_as_uint(f);
    return (u16)((x + 0x7FFFu + ((x >> 16) & 1u)) >> 16);
}
__device__ __forceinline__ void splitf(float v, u16& h, u16& l) {
    h = f2bf(v);
    l = f2bf(v - bf2f(h));   // v,h within 2x -> subtraction exact; residual ~2^-18 rel
}
__device__ __forceinline__ bf16x8 ld_bf8(const u16* p) {   // p 16B-aligned
    uint4 u = *(const uint4*)p;
    return __builtin_bit_cast(bf16x8, u);
}

// Build one split-weight workspace: hi/lo bf16 planes, row-major [rows][256].
__global__ __launch_bounds__(256)
void prep_w(const float* __restrict__ Wq, const float* __restrict__ Wk,
            const float* __restrict__ Wv, const float* __restrict__ Wo,
            const float* __restrict__ Wfc, u16* __restrict__ ws) {
    int e = blockIdx.x * 256 + threadIdx.x;     // 0 .. 327679
    float v; int hi_base, lo_base, idx;
    if (e < 196608) {                            // stacked Q,K,V rows 0..767
        int n = e >> 8, k = e & 255;
        const float* W = (n < 256) ? Wq : (n < 512 ? Wk : Wv);
        v = W[(n & 255) * 256 + k];
        hi_base = WS_QKV_HI; lo_base = WS_QKV_LO; idx = e;
    } else if (e < 262144) {
        idx = e - 196608; v = Wo[idx];
        hi_base = WS_WO_HI; lo_base = WS_WO_LO;
    } else {
        idx = e - 262144; v = Wfc[idx];
        hi_base = WS_WFC_HI; lo_base = WS_WFC_LO;
    }
    u16 h, l; splitf(v, h, l);
    ws[hi_base + idx] = h;
    ws[lo_base + idx] = l;
}

__device__ __forceinline__ void norm_stats(const float (&zv)[NG], int lane, int wid, int d,
                                           float (*s_wred)[NG][2], float* s_mu, float* s_rsd) {
    #pragma unroll
    for (int g = 0; g < NG; ++g) {
        float s = zv[g], q = zv[g] * zv[g];
        #pragma unroll
        for (int off = 32; off > 0; off >>= 1) {
            s += __shfl_xor(s, off, 64);
            q += __shfl_xor(q, off, 64);
        }
        if (lane == 0) { s_wred[wid][g][0] = s; s_wred[wid][g][1] = q; }
    }
    __syncthreads();
    if (d < NG) {
        float s = 0.f, q = 0.f;
        #pragma unroll
        for (int w = 0; w < 4; ++w) { s += s_wred[w][d][0]; q += s_wred[w][d][1]; }
        float mu = s * (1.f / 256.f);
        float var = fmaxf((q - 256.f * mu * mu) * (1.f / 255.f), 0.f);  // ddof=1
        s_mu[d] = mu;
        s_rsd[d] = 1.f / (sqrtf(var) + 1e-6f);
    }
    __syncthreads();
}

// B-fragment: rows of a row-major [rows][256] weight matrix (hi/lo split planes
// in ws, or inline-converted from f32 W).
template<bool PREP>
__device__ __forceinline__ void load_bfrag(const u16* wshi, const u16* wslo,
                                           const float* Wf, int row, int koff,
                                           bf16x8& bh, bf16x8& bl) {
    if constexpr (PREP) {
        const int off = row * 256 + koff;
        bh = ld_bf8(wshi + off);
        bl = ld_bf8(wslo + off);
    } else {
        const float* p = Wf + row * 256 + koff;
        float4 w0 = *(const float4*)p, w1 = *(const float4*)(p + 4);
        float wv[8] = {w0.x, w0.y, w0.z, w0.w, w1.x, w1.y, w1.z, w1.w};
        union { u16 s[8]; bf16x8 v; } H, L;
        #pragma unroll
        for (int j = 0; j < 8; ++j) splitf(wv[j], H.s[j], L.s[j]);
        bh = H.v; bl = L.v;
    }
}

template<bool PREP>
__global__ __launch_bounds__(256)
void enc_mfma(const float* __restrict__ x,  const float* __restrict__ adj,
              const float* __restrict__ Wq, const float* __restrict__ bq,
              const float* __restrict__ Wk, const float* __restrict__ bk,
              const float* __restrict__ Wv, const float* __restrict__ bv,
              const float* __restrict__ Wo, const float* __restrict__ bo,
              const float* __restrict__ Wfc,const float* __restrict__ bfc,
              const float* __restrict__ alpha, const float* __restrict__ beta,
              float* __restrict__ out, const u16* __restrict__ ws)
{
    extern __shared__ char smem[];
    u16*   hs_hi = (u16*)(smem + OFF_HS_HI);   // h / att / x1 split-bf16 [32][264]
    u16*   hs_lo = (u16*)(smem + OFF_HS_LO);
    float* qkvf  = (float*)(smem + OFF_QKV);   // Q,K,V f32 [3][32][268]; plane0 later = z/fc
    float* adjf  = (float*)(smem + OFF_ADJ);
    float* ss    = (float*)(smem + OFF_SS);    // scores [25][64]
    float (*s_wred)[NG][2] = (float(*)[NG][2])(smem + OFF_WRED);
    float* s_mu  = (float*)(smem + OFF_MU);
    float* s_rsd = (float*)(smem + OFF_RSD);

    const int bt = blockIdx.x;
    const int d = threadIdx.x;
    const int lane = d & 63, w = d >> 6;
    const int lm = lane & 15, quad = lane >> 4;
    const long base = (long)bt * (NG * ND);

    // ---- P0: stage adjacency ----
    for (int i = d; i < NG * NG; i += 256) adjf[i] = adj[i];
    __syncthreads();

    // ---- P1: h = adj @ x (VALU, f32), write split-bf16; zero pad rows ----
    {
        float acc[NG];
        #pragma unroll
        for (int g = 0; g < NG; ++g) acc[g] = 0.f;
        for (int n = 0; n < NG; ++n) {
            float xv = x[base + n * ND + d];
            #pragma unroll
            for (int g = 0; g < NG; ++g) acc[g] += adjf[g * NG + n] * xv;
        }
        #pragma unroll
        for (int g = 0; g < NG; ++g) {
            u16 h, l; splitf(acc[g], h, l);
            hs_hi[g * SB + d] = h; hs_lo[g * SB + d] = l;
        }
        for (int g = NG; g < 32; ++g) { hs_hi[g * SB + d] = 0; hs_lo[g * SB + d] = 0; }
    }
    __syncthreads();

    // ---- P2: QKV GEMM (MFMA). C[32,768]; wave w owns n in [w*192, w*192+192) ----
    {
        f32x4 acc[2][12];
        #pragma unroll
        for (int mt = 0; mt < 2; ++mt)
            #pragma unroll
            for (int nt = 0; nt < 12; ++nt) acc[mt][nt] = (f32x4)0.f;

        for (int k0 = 0; k0 < 256; k0 += 32) {
            const int koff = k0 + quad * 8;
            bf16x8 ah[2], al[2];
            #pragma unroll
            for (int mt = 0; mt < 2; ++mt) {
                const int off = (mt * 16 + lm) * SB + koff;
                ah[mt] = ld_bf8(hs_hi + off);
                al[mt] = ld_bf8(hs_lo + off);
            }
            #pragma unroll
            for (int nc = 0; nc < 12; nc += 4) {
                bf16x8 bh[4], bl[4];
                #pragma unroll
                for (int j = 0; j < 4; ++j) {
                    const int n0 = w * 192 + (nc + j) * 16;
                    const int mat = n0 >> 8;
                    const float* Wf = (mat == 0) ? Wq : (mat == 1 ? Wk : Wv);
                    load_bfrag<PREP>(ws + WS_QKV_HI, ws + WS_QKV_LO, Wf,
                                     PREP ? (n0 + lm) : ((n0 & 255) + lm), koff, bh[j], bl[j]);
                }
                #pragma unroll
                for (int j = 0; j < 4; ++j)
                    #pragma unroll
                    for (int mt = 0; mt < 2; ++mt)
                        acc[mt][nc + j] = __builtin_amdgcn_mfma_f32_16x16x32_bf16(ah[mt], bh[j], acc[mt][nc + j], 0, 0, 0);
                #pragma unroll
                for (int j = 0; j < 4; ++j)
                    #pragma unroll
                    for (int mt = 0; mt < 2; ++mt)
                        acc[mt][nc + j] = __builtin_amdgcn_mfma_f32_16x16x32_bf16(al[mt], bh[j], acc[mt][nc + j], 0, 0, 0);
                #pragma unroll
                for (int j = 0; j < 4; ++j)
                    #pragma unroll
                    for (int mt = 0; mt < 2; ++mt)
                        acc[mt][nc + j] = __builtin_amdgcn_mfma_f32_16x16x32_bf16(ah[mt], bl[j], acc[mt][nc + j], 0, 0, 0);
            }
        }
        // epilogue: + bias, write Q/K/V f32 planes
        #pragma unroll
        for (int nt = 0; nt < 12; ++nt) {
            const int n0 = w * 192 + nt * 16;
            const int mat = n0 >> 8, cb = (n0 & 255) + lm;
            const float* bp = (mat == 0) ? bq : (mat == 1 ? bk : bv);
            const float bb = bp[cb];
            float* plane = qkvf + mat * (32 * SF);
            #pragma unroll
            for (int mt = 0; mt < 2; ++mt)
                #pragma unroll
                for (int i = 0; i < 4; ++i)
                    plane[(mt * 16 + quad * 4 + i) * SF + cb] = acc[mt][nt][i] + bb;
        }
    }
    __syncthreads();

    // ---- P3: scores[g][h1][h2] = Q_g K_g^T / sqrt(32)  (f32) ----
    for (int i = d; i < NG * 64; i += 256) {
        const int g = i >> 6, hh = i & 63;
        const float4* q4 = (const float4*)(qkvf + 0 * 32 * SF + g * SF + (hh >> 3) * NHD);
        const float4* k4 = (const float4*)(qkvf + 1 * 32 * SF + g * SF + (hh & 7) * NHD);
        float s = 0.f;
        #pragma unroll
        for (int c = 0; c < 8; ++c) {
            float4 qa = q4[c], ka = k4[c];
            s += qa.x * ka.x + qa.y * ka.y + qa.z * ka.z + qa.w * ka.w;
        }
        ss[i] = s * 0.17677669529663687f;
    }
    __syncthreads();

    // ---- P4: softmax over g (dim=1) ----
    if (d < 64) {
        float m = -1e30f;
        for (int g = 0; g < NG; ++g) m = fmaxf(m, ss[g * 64 + d]);
        float den = 0.f;
        for (int g = 0; g < NG; ++g) den += expf(ss[g * 64 + d] - m);
        const float inv = 1.f / den;
        for (int g = 0; g < NG; ++g) ss[g * 64 + d] = expf(ss[g * 64 + d] - m) * inv;
    }
    __syncthreads();

    // ---- P5: att = w @ V (f32), write split-bf16 into hs (pad rows still 0) ----
    {
        const int h1 = d >> 5, hd = d & 31;
        const float* Vp = qkvf + 2 * 32 * SF;
        #pragma unroll
        for (int g = 0; g < NG; ++g) {
            float a = 0.f;
            #pragma unroll
            for (int h2 = 0; h2 < NH; ++h2)
                a += ss[g * 64 + h1 * 8 + h2] * Vp[g * SF + h2 * NHD + hd];
            u16 h, l; splitf(a, h, l);
            hs_hi[g * SB + d] = h; hs_lo[g * SB + d] = l;
        }
    }
    __syncthreads();

    // ---- P6: Wo GEMM (MFMA). C[32,256]; wave w owns n in [w*64, w*64+64) ----
    {
        f32x4 acc[2][4];
        #pragma unroll
        for (int mt = 0; mt < 2; ++mt)
            #pragma unroll
            for (int nt = 0; nt < 4; ++nt) acc[mt][nt] = (f32x4)0.f;

        for (int k0 = 0; k0 < 256; k0 += 32) {
            const int koff = k0 + quad * 8;
            bf16x8 ah[2], al[2];
            #pragma unroll
            for (int mt = 0; mt < 2; ++mt) {
                const int off = (mt * 16 + lm) * SB + koff;
                ah[mt] = ld_bf8(hs_hi + off);
                al[mt] = ld_bf8(hs_lo + off);
            }
            bf16x8 bh[4], bl[4];
            #pragma unroll
            for (int j = 0; j < 4; ++j)
                load_bfrag<PREP>(ws + WS_WO_HI, ws + WS_WO_LO, Wo,
                                 w * 64 + j * 16 + lm, koff, bh[j], bl[j]);
            #pragma unroll
            for (int j = 0; j < 4; ++j)
                #pragma unroll
                for (int mt = 0; mt < 2; ++mt)
                    acc[mt][j] = __builtin_amdgcn_mfma_f32_16x16x32_bf16(ah[mt], bh[j], acc[mt][j], 0, 0, 0);
            #pragma unroll
            for (int j = 0; j < 4; ++j)
                #pragma unroll
                for (int mt = 0; mt < 2; ++mt)
                    acc[mt][j] = __builtin_amdgcn_mfma_f32_16x16x32_bf16(al[mt], bh[j], acc[mt][j], 0, 0, 0);
            #pragma unroll
            for (int j = 0; j < 4; ++j)
                #pragma unroll
                for (int mt = 0; mt < 2; ++mt)
                    acc[mt][j] = __builtin_amdgcn_mfma_f32_16x16x32_bf16(ah[mt], bl[j], acc[mt][j], 0, 0, 0);
        }
        float* zs = qkvf;   // plane 0 (Q dead)
        #pragma unroll
        for (int nt = 0; nt < 4; ++nt) {
            const int col = w * 64 + nt * 16 + lm;
            const float bb = bo[col];
            #pragma unroll
            for (int mt = 0; mt < 2; ++mt)
                #pragma unroll
                for (int i = 0; i < 4; ++i)
                    zs[(mt * 16 + quad * 4 + i) * SF + col] = acc[mt][nt][i] + bb;
        }
    }
    __syncthreads();

    // ---- P7: norm1; keep x1 in regs; write x1 split-bf16 into hs ----
    float zv[NG];
    {
        float* zs = qkvf;
        #pragma unroll
        for (int g = 0; g < NG; ++g) zv[g] = zs[g * SF + d] + x[base + g * ND + d];
    }
    norm_stats(zv, lane, w, d, s_wred, s_mu, s_rsd);
    const float af = alpha[d], bef = beta[d];
    #pragma unroll
    for (int g = 0; g < NG; ++g) {
        const float x1 = af * (zv[g] - s_mu[g]) * s_rsd[g] + bef;
        zv[g] = x1;
        u16 h, l; splitf(x1, h, l);
        hs_hi[g * SB + d] = h; hs_lo[g * SB + d] = l;
    }
    __syncthreads();

    // ---- P8: Wfc GEMM (MFMA); epilogue relu(acc+bfc) -> zs ----
    {
        f32x4 acc[2][4];
        #pragma unroll
        for (int mt = 0; mt < 2; ++mt)
            #pragma unroll
            for (int nt = 0; nt < 4; ++nt) acc[mt][nt] = (f32x4)0.f;

        for (int k0 = 0; k0 < 256; k0 += 32) {
            const int koff = k0 + quad * 8;
            bf16x8 ah[2], al[2];
            #pragma unroll
            for (int mt = 0; mt < 2; ++mt) {
                const int off = (mt * 16 + lm) * SB + koff;
                ah[mt] = ld_bf8(hs_hi + off);
                al[mt] = ld_bf8(hs_lo + off);
            }
            bf16x8 bh[4], bl[4];
            #pragma unroll
            for (int j = 0; j < 4; ++j)
                load_bfrag<PREP>(ws + WS_WFC_HI, ws + WS_WFC_LO, Wfc,
                                 w * 64 + j * 16 + lm, koff, bh[j], bl[j]);
            #pragma unroll
            for (int j = 0; j < 4; ++j)
                #pragma unroll
                for (int mt = 0; mt < 2; ++mt)
                    acc[mt][j] = __builtin_amdgcn_mfma_f32_16x16x32_bf16(ah[mt], bh[j], acc[mt][j], 0, 0, 0);
            #pragma unroll
            for (int j = 0; j < 4; ++j)
                #pragma unroll
                for (int mt = 0; mt < 2; ++mt)
                    acc[mt][j] = __builtin_amdgcn_mfma_f32_16x16x32_bf16(al[mt], bh[j], acc[mt][j], 0, 0, 0);
            #pragma unroll
            for (int j = 0; j < 4; ++j)
                #pragma unroll
                for (int mt = 0; mt < 2; ++mt)
                    acc[mt][j] = __builtin_amdgcn_mfma_f32_16x16x32_bf16(ah[mt], bl[j], acc[mt][j], 0, 0, 0);
        }
        float* zs = qkvf;
        #pragma unroll
        for (int nt = 0; nt < 4; ++nt) {
            const int col = w * 64 + nt * 16 + lm;
            const float bb = bfc[col];
            #pragma unroll
            for (int mt = 0; mt < 2; ++mt)
                #pragma unroll
                for (int i = 0; i < 4; ++i)
                    zs[(mt * 16 + quad * 4 + i) * SF + col] = fmaxf(acc[mt][nt][i] + bb, 0.f);
        }
    }
    __syncthreads();

    // ---- P9: norm2 -> out ----
    float z2[NG];
    {
        float* zs = qkvf;
        #pragma unroll
        for (int g = 0; g < NG; ++g) z2[g] = zv[g] + zs[g * SF + d];
    }
    norm_stats(z2, lane, w, d, s_wred, s_mu, s_rsd);
    #pragma unroll
    for (int g = 0; g < NG; ++g)
        out[base + g * ND + d] = af * (z2[g] - s_mu[g]) * s_rsd[g] + bef;
}

extern "C" void kernel_launch(void* const* d_in, const int* in_sizes, int n_in,
                              void* d_out, int out_size, void* d_ws, size_t ws_size,
                              hipStream_t stream) {
    (void)in_sizes; (void)n_in; (void)out_size;
    const float* x     = (const float*)d_in[0];
    const float* adj   = (const float*)d_in[1];
    const float* Wq    = (const float*)d_in[2];
    const float* bq    = (const float*)d_in[3];
    const float* Wk    = (const float*)d_in[4];
    const float* bk    = (const float*)d_in[5];
    const float* Wv    = (const float*)d_in[6];
    const float* bv    = (const float*)d_in[7];
    const float* Wo    = (const float*)d_in[8];
    const float* bo    = (const float*)d_in[9];
    const float* Wfc   = (const float*)d_in[10];
    const float* bfc   = (const float*)d_in[11];
    const float* alpha = (const float*)d_in[12];
    const float* beta  = (const float*)d_in[13];
    float* out = (float*)d_out;
    u16* ws = (u16*)d_ws;

    const bool prep = (ws_size >= WS_NEED_BYTES);

    static int attr_done_true = 0, attr_done_false = 0;  // idempotent attr set (not a work guard)
    (void)attr_done_true; (void)attr_done_false;
    hipFuncSetAttribute((const void*)enc_mfma<true>,
                        hipFuncAttributeMaxDynamicSharedMemorySize, SMEM_TOT);
    hipFuncSetAttribute((const void*)enc_mfma<false>,
                        hipFuncAttributeMaxDynamicSharedMemorySize, SMEM_TOT);

    if (prep) {
        prep_w<<<dim3(1280), dim3(256), 0, stream>>>(Wq, Wk, Wv, Wo, Wfc, ws);
        enc_mfma<true><<<dim3(NB * NT), dim3(256), SMEM_TOT, stream>>>(
            x, adj, Wq, bq, Wk, bk, Wv, bv, Wo, bo, Wfc, bfc, alpha, beta, out, ws);
    } else {
        enc_mfma<false><<<dim3(NB * NT), dim3(256), SMEM_TOT, stream>>>(
            x, adj, Wq, bq, Wk, bk, Wv, bv, Wo, bo, Wfc, bfc, alpha, beta, out, ws);
    }
}

// Round 4
// 1028.055 us; speedup vs baseline: 2.5924x; 1.1888x over previous
//
#include <hip/hip_runtime.h>

#define NB 32
#define NT 120
#define NG 25
#define ND 256
#define NH 8
#define NHD 32
#define NTH 512

typedef unsigned short u16;
typedef unsigned int u32;

typedef __bf16 bf16x8 __attribute__((ext_vector_type(8)));
typedef float  f32x4  __attribute__((ext_vector_type(4)));

// ---- LDS layout (dynamic, 146768 B) ----
#define SB 264                    // bf16 row stride (elements)
#define SF 268                    // f32 row stride (elements)
#define OFF_HS_HI 0               // u16[32*264] = 16896
#define OFF_HS_LO 16896
#define OFF_QKV   33792           // f32[3][32][268] = 102912
#define OFF_ADJ   136704          // f32[652] = 2608; reused as softmax scratch [8][64]
#define OFF_SS    139312          // f32[1600] = 6400
#define OFF_WRED  145712          // f32[8][13][2] = 832
#define OFF_MU    146544          // f32[25] (pad 112)
#define OFF_RSD   146656          // f32[25] (pad 112)
#define SMEM_TOT  146768

// ---- ws split-weight plane offsets (u16 elements) ----
#define WS_QKV_HI 0
#define WS_QKV_LO 196608
#define WS_WO_HI  393216
#define WS_WO_LO  458752
#define WS_WFC_HI 524288
#define WS_WFC_LO 589824
#define WS_NEED_BYTES (655360ull * 2ull)   // 1,310,720 B

__device__ __forceinline__ float bf2f(u16 u) { return __uint_as_float(((u32)u) << 16); }
__device__ __forceinline__ u16 f2bf(float f) {   // round-to-nearest-even
    u32 x = __float_as_uint(f);
    return (u16)((x + 0x7FFFu + ((x >> 16) & 1u)) >> 16);
}
__device__ __forceinline__ void splitf(float v, u16& h, u16& l) {
    h = f2bf(v);
    l = f2bf(v - bf2f(h));   // residual ~2^-18 rel
}
__device__ __forceinline__ bf16x8 ld_bf8(const u16* p) {   // p 16B-aligned
    uint4 u = *(const uint4*)p;
    return __builtin_bit_cast(bf16x8, u);
}

// Build split-weight workspace: hi/lo bf16 planes, row-major [rows][256].
__global__ __launch_bounds__(256)
void prep_w(const float* __restrict__ Wq, const float* __restrict__ Wk,
            const float* __restrict__ Wv, const float* __restrict__ Wo,
            const float* __restrict__ Wfc, u16* __restrict__ ws) {
    int e = blockIdx.x * 256 + threadIdx.x;     // 0 .. 327679
    float v; int hi_base, lo_base, idx;
    if (e < 196608) {                            // stacked Q,K,V rows 0..767
        int n = e >> 8, k = e & 255;
        const float* W = (n < 256) ? Wq : (n < 512 ? Wk : Wv);
        v = W[(n & 255) * 256 + k];
        hi_base = WS_QKV_HI; lo_base = WS_QKV_LO; idx = e;
    } else if (e < 262144) {
        idx = e - 196608; v = Wo[idx];
        hi_base = WS_WO_HI; lo_base = WS_WO_LO;
    } else {
        idx = e - 262144; v = Wfc[idx];
        hi_base = WS_WFC_HI; lo_base = WS_WFC_LO;
    }
    u16 h, l; splitf(v, h, l);
    ws[hi_base + idx] = h;
    ws[lo_base + idx] = l;
}

// 512-thread norm stats: thread (d, rep) holds zv[i] for g = g0+i, i < gn.
// Waves 0-3 are rep 0 (g 0-12), waves 4-7 rep 1 (g 13-24).
__device__ __forceinline__ void norm_stats8(const float* zv, int g0, int gn,
                                            int lane, int wid, int tid,
                                            float (*s_wred)[13][2], float* s_mu, float* s_rsd) {
    (void)g0;
    #pragma unroll
    for (int i = 0; i < 13; ++i) {
        if (i >= gn) break;
        float s = zv[i], q = zv[i] * zv[i];
        #pragma unroll
        for (int off = 32; off > 0; off >>= 1) {
            s += __shfl_xor(s, off, 64);
            q += __shfl_xor(q, off, 64);
        }
        if (lane == 0) { s_wred[wid][i][0] = s; s_wred[wid][i][1] = q; }
    }
    __syncthreads();
    if (tid < NG) {
        const int g = tid;
        const int wb = (g < 13) ? 0 : 4, lg = (g < 13) ? g : g - 13;
        float s = 0.f, q = 0.f;
        #pragma unroll
        for (int w = 0; w < 4; ++w) { s += s_wred[wb + w][lg][0]; q += s_wred[wb + w][lg][1]; }
        float mu = s * (1.f / 256.f);
        float var = fmaxf((q - 256.f * mu * mu) * (1.f / 255.f), 0.f);  // ddof=1
        s_mu[g] = mu;
        s_rsd[g] = 1.f / (sqrtf(var) + 1e-6f);
    }
    __syncthreads();
}

// B-fragment: rows of row-major [rows][256] weights (split planes in ws, or inline f32).
template<bool PREP>
__device__ __forceinline__ void load_bfrag(const u16* wshi, const u16* wslo,
                                           const float* Wf, int row, int koff,
                                           bf16x8& bh, bf16x8& bl) {
    if constexpr (PREP) {
        const int off = row * 256 + koff;
        bh = ld_bf8(wshi + off);
        bl = ld_bf8(wslo + off);
    } else {
        const float* p = Wf + row * 256 + koff;
        float4 w0 = *(const float4*)p, w1 = *(const float4*)(p + 4);
        float wv[8] = {w0.x, w0.y, w0.z, w0.w, w1.x, w1.y, w1.z, w1.w};
        union { u16 s[8]; bf16x8 v; } H, L;
        #pragma unroll
        for (int j = 0; j < 8; ++j) splitf(wv[j], H.s[j], L.s[j]);
        bh = H.v; bl = L.v;
    }
}

template<bool PREP>
__global__ __launch_bounds__(NTH, 2)
void enc_mfma(const float* __restrict__ x,  const float* __restrict__ adj,
              const float* __restrict__ Wq, const float* __restrict__ bq,
              const float* __restrict__ Wk, const float* __restrict__ bk,
              const float* __restrict__ Wv, const float* __restrict__ bv,
              const float* __restrict__ Wo, const float* __restrict__ bo,
              const float* __restrict__ Wfc,const float* __restrict__ bfc,
              const float* __restrict__ alpha, const float* __restrict__ beta,
              float* __restrict__ out, const u16* __restrict__ ws)
{
    extern __shared__ char smem[];
    u16*   hs_hi = (u16*)(smem + OFF_HS_HI);   // h / att / x1 split-bf16 [32][264]
    u16*   hs_lo = (u16*)(smem + OFF_HS_LO);
    float* qkvf  = (float*)(smem + OFF_QKV);   // Q,K,V f32 [3][32][268]; plane0 later = z/fc
    float* adjf  = (float*)(smem + OFF_ADJ);   // also softmax scratch [8][64]
    float* ss    = (float*)(smem + OFF_SS);    // scores [25][64]
    float (*s_wred)[13][2] = (float(*)[13][2])(smem + OFF_WRED);
    float* s_mu  = (float*)(smem + OFF_MU);
    float* s_rsd = (float*)(smem + OFF_RSD);

    const int bt = blockIdx.x;
    const int tid = threadIdx.x;
    const int d = tid & 255, rep = tid >> 8;
    const int lane = tid & 63, wid = tid >> 6;          // wave id 0-7
    const int lm = lane & 15, quad = lane >> 4;
    const int g0 = rep ? 13 : 0, gn = rep ? 12 : 13;
    const long base = (long)bt * (NG * ND);

    // ---- P0: stage adjacency ----
    for (int i = tid; i < NG * NG; i += NTH) adjf[i] = adj[i];
    __syncthreads();

    // ---- P1: h = adj @ x (VALU, f32), write split-bf16; rep1 zeros pad rows ----
    {
        float acc[13];
        #pragma unroll
        for (int i = 0; i < 13; ++i) acc[i] = 0.f;
        for (int n = 0; n < NG; ++n) {
            float xv = x[base + n * ND + d];
            #pragma unroll
            for (int i = 0; i < 13; ++i)
                acc[i] += adjf[(g0 + i) * NG + n] * xv;   // i==12,rep1 reads in-bounds pad; never stored
        }
        #pragma unroll
        for (int i = 0; i < 13; ++i) {
            if (i >= gn) break;
            u16 h, l; splitf(acc[i], h, l);
            hs_hi[(g0 + i) * SB + d] = h; hs_lo[(g0 + i) * SB + d] = l;
        }
        if (rep) {
            #pragma unroll
            for (int g = NG; g < 32; ++g) { hs_hi[g * SB + d] = 0; hs_lo[g * SB + d] = 0; }
        }
    }
    __syncthreads();

    // ---- P2: QKV GEMM (MFMA). C[32,768]; wave wid owns cols [wid*96, wid*96+96) ----
    {
        f32x4 acc[2][6];
        #pragma unroll
        for (int mt = 0; mt < 2; ++mt)
            #pragma unroll
            for (int nt = 0; nt < 6; ++nt) acc[mt][nt] = (f32x4)0.f;

        for (int k0 = 0; k0 < 256; k0 += 32) {
            const int koff = k0 + quad * 8;
            bf16x8 ah[2], al[2];
            #pragma unroll
            for (int mt = 0; mt < 2; ++mt) {
                const int off = (mt * 16 + lm) * SB + koff;
                ah[mt] = ld_bf8(hs_hi + off);
                al[mt] = ld_bf8(hs_lo + off);
            }
            bf16x8 bh[6], bl[6];
            #pragma unroll
            for (int j = 0; j < 6; ++j) {
                const int n0 = wid * 96 + j * 16;
                const int mat = n0 >> 8;
                const float* Wf = (mat == 0) ? Wq : (mat == 1 ? Wk : Wv);
                load_bfrag<PREP>(ws + WS_QKV_HI, ws + WS_QKV_LO, Wf,
                                 PREP ? (n0 + lm) : ((n0 & 255) + lm), koff, bh[j], bl[j]);
            }
            #pragma unroll
            for (int j = 0; j < 6; ++j)
                #pragma unroll
                for (int mt = 0; mt < 2; ++mt)
                    acc[mt][j] = __builtin_amdgcn_mfma_f32_16x16x32_bf16(ah[mt], bh[j], acc[mt][j], 0, 0, 0);
            #pragma unroll
            for (int j = 0; j < 6; ++j)
                #pragma unroll
                for (int mt = 0; mt < 2; ++mt)
                    acc[mt][j] = __builtin_amdgcn_mfma_f32_16x16x32_bf16(al[mt], bh[j], acc[mt][j], 0, 0, 0);
            #pragma unroll
            for (int j = 0; j < 6; ++j)
                #pragma unroll
                for (int mt = 0; mt < 2; ++mt)
                    acc[mt][j] = __builtin_amdgcn_mfma_f32_16x16x32_bf16(ah[mt], bl[j], acc[mt][j], 0, 0, 0);
        }
        // epilogue: + bias, write Q/K/V f32 planes
        #pragma unroll
        for (int nt = 0; nt < 6; ++nt) {
            const int n0 = wid * 96 + nt * 16;
            const int mat = n0 >> 8, cb = (n0 & 255) + lm;
            const float* bp = (mat == 0) ? bq : (mat == 1 ? bk : bv);
            const float bb = bp[cb];
            float* plane = qkvf + mat * (32 * SF);
            #pragma unroll
            for (int mt = 0; mt < 2; ++mt)
                #pragma unroll
                for (int i = 0; i < 4; ++i)
                    plane[(mt * 16 + quad * 4 + i) * SF + cb] = acc[mt][nt][i] + bb;
        }
    }
    __syncthreads();

    // ---- P3: scores[g][h1][h2] = Q_g K_g^T / sqrt(32)  (f32) ----
    for (int i = tid; i < NG * 64; i += NTH) {
        const int g = i >> 6, hh = i & 63;
        const float4* q4 = (const float4*)(qkvf + 0 * 32 * SF + g * SF + (hh >> 3) * NHD);
        const float4* k4 = (const float4*)(qkvf + 1 * 32 * SF + g * SF + (hh & 7) * NHD);
        float s = 0.f;
        #pragma unroll
        for (int c = 0; c < 8; ++c) {
            float4 qa = q4[c], ka = k4[c];
            s += qa.x * ka.x + qa.y * ka.y + qa.z * ka.z + qa.w * ka.w;
        }
        ss[i] = s * 0.17677669529663687f;
    }
    __syncthreads();

    // ---- P4: softmax over g (dim=1), 8-way parallel over g-partitions ----
    {
        float* s_sm = adjf;                       // [8][64] scratch (adjf dead)
        const int col = tid & 63, part = tid >> 6;
        float m = -1e30f;
        for (int g = part; g < NG; g += 8) m = fmaxf(m, ss[g * 64 + col]);
        s_sm[part * 64 + col] = m;
        __syncthreads();
        float cm = -1e30f;
        #pragma unroll
        for (int p = 0; p < 8; ++p) cm = fmaxf(cm, s_sm[p * 64 + col]);
        __syncthreads();                          // all reads done before overwrite
        float den = 0.f;
        for (int g = part; g < NG; g += 8) {
            float e = expf(ss[g * 64 + col] - cm);
            ss[g * 64 + col] = e;
            den += e;
        }
        s_sm[part * 64 + col] = den;
        __syncthreads();
        float tden = 0.f;
        #pragma unroll
        for (int p = 0; p < 8; ++p) tden += s_sm[p * 64 + col];
        const float inv = 1.f / tden;
        for (int g = part; g < NG; g += 8) ss[g * 64 + col] *= inv;
    }
    __syncthreads();

    // ---- P5: att = w @ V (f32), write split-bf16 into hs (pad rows still 0) ----
    {
        const int h1 = (tid >> 5) & 7, hd = tid & 31;   // col = d
        const float* Vp = qkvf + 2 * 32 * SF;
        #pragma unroll
        for (int i = 0; i < 13; ++i) {
            if (i >= gn) break;
            const int g = g0 + i;
            float a = 0.f;
            #pragma unroll
            for (int h2 = 0; h2 < NH; ++h2)
                a += ss[g * 64 + h1 * 8 + h2] * Vp[g * SF + h2 * NHD + hd];
            u16 h, l; splitf(a, h, l);
            hs_hi[g * SB + d] = h; hs_lo[g * SB + d] = l;
        }
    }
    __syncthreads();

    // ---- P6: Wo GEMM (MFMA). C[32,256]; wave wid owns cols [wid*32, wid*32+32) ----
    {
        f32x4 acc[2][2];
        #pragma unroll
        for (int mt = 0; mt < 2; ++mt)
            #pragma unroll
            for (int nt = 0; nt < 2; ++nt) acc[mt][nt] = (f32x4)0.f;

        for (int k0 = 0; k0 < 256; k0 += 32) {
            const int koff = k0 + quad * 8;
            bf16x8 ah[2], al[2];
            #pragma unroll
            for (int mt = 0; mt < 2; ++mt) {
                const int off = (mt * 16 + lm) * SB + koff;
                ah[mt] = ld_bf8(hs_hi + off);
                al[mt] = ld_bf8(hs_lo + off);
            }
            bf16x8 bh[2], bl[2];
            #pragma unroll
            for (int j = 0; j < 2; ++j)
                load_bfrag<PREP>(ws + WS_WO_HI, ws + WS_WO_LO, Wo,
                                 wid * 32 + j * 16 + lm, koff, bh[j], bl[j]);
            #pragma unroll
            for (int j = 0; j < 2; ++j)
                #pragma unroll
                for (int mt = 0; mt < 2; ++mt)
                    acc[mt][j] = __builtin_amdgcn_mfma_f32_16x16x32_bf16(ah[mt], bh[j], acc[mt][j], 0, 0, 0);
            #pragma unroll
            for (int j = 0; j < 2; ++j)
                #pragma unroll
                for (int mt = 0; mt < 2; ++mt)
                    acc[mt][j] = __builtin_amdgcn_mfma_f32_16x16x32_bf16(al[mt], bh[j], acc[mt][j], 0, 0, 0);
            #pragma unroll
            for (int j = 0; j < 2; ++j)
                #pragma unroll
                for (int mt = 0; mt < 2; ++mt)
                    acc[mt][j] = __builtin_amdgcn_mfma_f32_16x16x32_bf16(ah[mt], bl[j], acc[mt][j], 0, 0, 0);
        }
        float* zs = qkvf;   // plane 0 (Q dead)
        #pragma unroll
        for (int nt = 0; nt < 2; ++nt) {
            const int col = wid * 32 + nt * 16 + lm;
            const float bb = bo[col];
            #pragma unroll
            for (int mt = 0; mt < 2; ++mt)
                #pragma unroll
                for (int i = 0; i < 4; ++i)
                    zs[(mt * 16 + quad * 4 + i) * SF + col] = acc[mt][nt][i] + bb;
        }
    }
    __syncthreads();

    // ---- P7: norm1; keep x1 in regs; write x1 split-bf16 into hs ----
    float zv[13];
    {
        float* zs = qkvf;
        #pragma unroll
        for (int i = 0; i < 13; ++i) {
            if (i >= gn) break;
            zv[i] = zs[(g0 + i) * SF + d] + x[base + (g0 + i) * ND + d];
        }
    }
    norm_stats8(zv, g0, gn, lane, wid, tid, s_wred, s_mu, s_rsd);
    const float af = alpha[d], bef = beta[d];
    #pragma unroll
    for (int i = 0; i < 13; ++i) {
        if (i >= gn) break;
        const float x1 = af * (zv[i] - s_mu[g0 + i]) * s_rsd[g0 + i] + bef;
        zv[i] = x1;
        u16 h, l; splitf(x1, h, l);
        hs_hi[(g0 + i) * SB + d] = h; hs_lo[(g0 + i) * SB + d] = l;
    }
    __syncthreads();

    // ---- P8: Wfc GEMM (MFMA); epilogue relu(acc+bfc) -> zs ----
    {
        f32x4 acc[2][2];
        #pragma unroll
        for (int mt = 0; mt < 2; ++mt)
            #pragma unroll
            for (int nt = 0; nt < 2; ++nt) acc[mt][nt] = (f32x4)0.f;

        for (int k0 = 0; k0 < 256; k0 += 32) {
            const int koff = k0 + quad * 8;
            bf16x8 ah[2], al[2];
            #pragma unroll
            for (int mt = 0; mt < 2; ++mt) {
                const int off = (mt * 16 + lm) * SB + koff;
                ah[mt] = ld_bf8(hs_hi + off);
                al[mt] = ld_bf8(hs_lo + off);
            }
            bf16x8 bh[2], bl[2];
            #pragma unroll
            for (int j = 0; j < 2; ++j)
                load_bfrag<PREP>(ws + WS_WFC_HI, ws + WS_WFC_LO, Wfc,
                                 wid * 32 + j * 16 + lm, koff, bh[j], bl[j]);
            #pragma unroll
            for (int j = 0; j < 2; ++j)
                #pragma unroll
                for (int mt = 0; mt < 2; ++mt)
                    acc[mt][j] = __builtin_amdgcn_mfma_f32_16x16x32_bf16(ah[mt], bh[j], acc[mt][j], 0, 0, 0);
            #pragma unroll
            for (int j = 0; j < 2; ++j)
                #pragma unroll
                for (int mt = 0; mt < 2; ++mt)
                    acc[mt][j] = __builtin_amdgcn_mfma_f32_16x16x32_bf16(al[mt], bh[j], acc[mt][j], 0, 0, 0);
            #pragma unroll
            for (int j = 0; j < 2; ++j)
                #pragma unroll
                for (int mt = 0; mt < 2; ++mt)
                    acc[mt][j] = __builtin_amdgcn_mfma_f32_16x16x32_bf16(ah[mt], bl[j], acc[mt][j], 0, 0, 0);
        }
        float* zs = qkvf;
        #pragma unroll
        for (int nt = 0; nt < 2; ++nt) {
            const int col = wid * 32 + nt * 16 + lm;
            const float bb = bfc[col];
            #pragma unroll
            for (int mt = 0; mt < 2; ++mt)
                #pragma unroll
                for (int i = 0; i < 4; ++i)
                    zs[(mt * 16 + quad * 4 + i) * SF + col] = fmaxf(acc[mt][nt][i] + bb, 0.f);
        }
    }
    __syncthreads();

    // ---- P9: norm2 -> out ----
    float z2[13];
    {
        float* zs = qkvf;
        #pragma unroll
        for (int i = 0; i < 13; ++i) {
            if (i >= gn) break;
            z2[i] = zv[i] + zs[(g0 + i) * SF + d];
        }
    }
    norm_stats8(z2, g0, gn, lane, wid, tid, s_wred, s_mu, s_rsd);
    #pragma unroll
    for (int i = 0; i < 13; ++i) {
        if (i >= gn) break;
        out[base + (g0 + i) * ND + d] = af * (z2[i] - s_mu[g0 + i]) * s_rsd[g0 + i] + bef;
    }
}

extern "C" void kernel_launch(void* const* d_in, const int* in_sizes, int n_in,
                              void* d_out, int out_size, void* d_ws, size_t ws_size,
                              hipStream_t stream) {
    (void)in_sizes; (void)n_in; (void)out_size;
    const float* x     = (const float*)d_in[0];
    const float* adj   = (const float*)d_in[1];
    const float* Wq    = (const float*)d_in[2];
    const float* bq    = (const float*)d_in[3];
    const float* Wk    = (const float*)d_in[4];
    const float* bk    = (const float*)d_in[5];
    const float* Wv    = (const float*)d_in[6];
    const float* bv    = (const float*)d_in[7];
    const float* Wo    = (const float*)d_in[8];
    const float* bo    = (const float*)d_in[9];
    const float* Wfc   = (const float*)d_in[10];
    const float* bfc   = (const float*)d_in[11];
    const float* alpha = (const float*)d_in[12];
    const float* beta  = (const float*)d_in[13];
    float* out = (float*)d_out;
    u16* ws = (u16*)d_ws;

    const bool prep = (ws_size >= WS_NEED_BYTES);

    hipFuncSetAttribute((const void*)enc_mfma<true>,
                        hipFuncAttributeMaxDynamicSharedMemorySize, SMEM_TOT);
    hipFuncSetAttribute((const void*)enc_mfma<false>,
                        hipFuncAttributeMaxDynamicSharedMemorySize, SMEM_TOT);

    if (prep) {
        prep_w<<<dim3(1280), dim3(256), 0, stream>>>(Wq, Wk, Wv, Wo, Wfc, ws);
        enc_mfma<true><<<dim3(NB * NT), dim3(NTH), SMEM_TOT, stream>>>(
            x, adj, Wq, bq, Wk, bk, Wv, bv, Wo, bo, Wfc, bfc, alpha, beta, out, ws);
    } else {
        enc_mfma<false><<<dim3(NB * NT), dim3(NTH), SMEM_TOT, stream>>>(
            x, adj, Wq, bq, Wk, bk, Wv, bv, Wo, bo, Wfc, bfc, alpha, beta, out, ws);
    }
}

// Round 5
// 983.877 us; speedup vs baseline: 2.7088x; 1.0449x over previous
//
#include <hip/hip_runtime.h>

#define NB 32
#define NT 120
#define NG 25
#define ND 256
#define NH 8
#define NHD 32
#define NTH 512

typedef unsigned short u16;
typedef unsigned int u32;

typedef __bf16 bf16x8 __attribute__((ext_vector_type(8)));
typedef float  f32x4  __attribute__((ext_vector_type(4)));

// ---- LDS layout (dynamic, 146768 B) ----
#define SB 264                    // bf16 row stride (elements)
#define SF 268                    // f32 row stride (elements)
#define OFF_HS_HI 0               // u16[32*264] = 16896
#define OFF_HS_LO 16896
#define OFF_QKV   33792           // f32[3][32][268] = 102912
#define OFF_ADJ   136704          // f32[652] = 2608; reused as softmax scratch [8][64]
#define OFF_SS    139312          // f32[1600] = 6400
#define OFF_WRED  145712          // f32[8][13][2] = 832
#define OFF_MU    146544          // f32[25] (pad 112)
#define OFF_RSD   146656          // f32[25] (pad 112)
#define SMEM_TOT  146768

// ---- ws split-weight plane offsets (u16 elements) ----
#define WS_QKV_HI 0
#define WS_QKV_LO 196608
#define WS_WO_HI  393216
#define WS_WO_LO  458752
#define WS_WFC_HI 524288
#define WS_WFC_LO 589824
#define WS_NEED_BYTES (655360ull * 2ull)   // 1,310,720 B

__device__ __forceinline__ float bf2f(u16 u) { return __uint_as_float(((u32)u) << 16); }
__device__ __forceinline__ u16 f2bf(float f) {   // round-to-nearest-even
    u32 x = __float_as_uint(f);
    return (u16)((x + 0x7FFFu + ((x >> 16) & 1u)) >> 16);
}
__device__ __forceinline__ void splitf(float v, u16& h, u16& l) {
    h = f2bf(v);
    l = f2bf(v - bf2f(h));   // residual ~2^-18 rel
}
__device__ __forceinline__ bf16x8 ld_bf8(const u16* p) {   // p 16B-aligned
    uint4 u = *(const uint4*)p;
    return __builtin_bit_cast(bf16x8, u);
}

// Build split-weight workspace: hi/lo bf16 planes, row-major [rows][256].
__global__ __launch_bounds__(256)
void prep_w(const float* __restrict__ Wq, const float* __restrict__ Wk,
            const float* __restrict__ Wv, const float* __restrict__ Wo,
            const float* __restrict__ Wfc, u16* __restrict__ ws) {
    int e = blockIdx.x * 256 + threadIdx.x;     // 0 .. 327679
    float v; int hi_base, lo_base, idx;
    if (e < 196608) {                            // stacked Q,K,V rows 0..767
        int n = e >> 8, k = e & 255;
        const float* W = (n < 256) ? Wq : (n < 512 ? Wk : Wv);
        v = W[(n & 255) * 256 + k];
        hi_base = WS_QKV_HI; lo_base = WS_QKV_LO; idx = e;
    } else if (e < 262144) {
        idx = e - 196608; v = Wo[idx];
        hi_base = WS_WO_HI; lo_base = WS_WO_LO;
    } else {
        idx = e - 262144; v = Wfc[idx];
        hi_base = WS_WFC_HI; lo_base = WS_WFC_LO;
    }
    u16 h, l; splitf(v, h, l);
    ws[hi_base + idx] = h;
    ws[lo_base + idx] = l;
}

// 512-thread norm stats: waves 0-3 hold g 0-12 (rep 0), waves 4-7 g 13-24.
__device__ __forceinline__ void norm_stats8(const float* zv, int gn,
                                            int lane, int wid, int tid,
                                            float (*s_wred)[13][2], float* s_mu, float* s_rsd) {
    #pragma unroll
    for (int i = 0; i < 13; ++i) {
        if (i >= gn) break;
        float s = zv[i], q = zv[i] * zv[i];
        #pragma unroll
        for (int off = 32; off > 0; off >>= 1) {
            s += __shfl_xor(s, off, 64);
            q += __shfl_xor(q, off, 64);
        }
        if (lane == 0) { s_wred[wid][i][0] = s; s_wred[wid][i][1] = q; }
    }
    __syncthreads();
    if (tid < NG) {
        const int g = tid;
        const int wb = (g < 13) ? 0 : 4, lg = (g < 13) ? g : g - 13;
        float s = 0.f, q = 0.f;
        #pragma unroll
        for (int w = 0; w < 4; ++w) { s += s_wred[wb + w][lg][0]; q += s_wred[wb + w][lg][1]; }
        float mu = s * (1.f / 256.f);
        float var = fmaxf((q - 256.f * mu * mu) * (1.f / 255.f), 0.f);  // ddof=1
        s_mu[g] = mu;
        s_rsd[g] = 1.f / (sqrtf(var) + 1e-6f);
    }
    __syncthreads();
}

// B-fragment: rows of row-major [rows][256] weights (split planes in ws, or inline f32).
template<bool PREP>
__device__ __forceinline__ void load_bfrag(const u16* wshi, const u16* wslo,
                                           const float* Wf, int row, int koff,
                                           bf16x8& bh, bf16x8& bl) {
    if constexpr (PREP) {
        const int off = row * 256 + koff;
        bh = ld_bf8(wshi + off);
        bl = ld_bf8(wslo + off);
    } else {
        const float* p = Wf + row * 256 + koff;
        float4 w0 = *(const float4*)p, w1 = *(const float4*)(p + 4);
        float wv[8] = {w0.x, w0.y, w0.z, w0.w, w1.x, w1.y, w1.z, w1.w};
        union { u16 s[8]; bf16x8 v; } H, L;
        #pragma unroll
        for (int j = 0; j < 8; ++j) splitf(wv[j], H.s[j], L.s[j]);
        bh = H.v; bl = L.v;
    }
}

template<bool PREP>
__global__ __launch_bounds__(NTH, 2)
void enc_mfma(const float* __restrict__ x,  const float* __restrict__ adj,
              const float* __restrict__ Wq, const float* __restrict__ bq,
              const float* __restrict__ Wk, const float* __restrict__ bk,
              const float* __restrict__ Wv, const float* __restrict__ bv,
              const float* __restrict__ Wo, const float* __restrict__ bo,
              const float* __restrict__ Wfc,const float* __restrict__ bfc,
              const float* __restrict__ alpha, const float* __restrict__ beta,
              float* __restrict__ out, const u16* __restrict__ ws)
{
    extern __shared__ char smem[];
    u16*   hs_hi = (u16*)(smem + OFF_HS_HI);   // h / att / x1 split-bf16 [32][264]
    u16*   hs_lo = (u16*)(smem + OFF_HS_LO);
    float* qkvf  = (float*)(smem + OFF_QKV);   // Q,K,V f32 [3][32][268]; plane0 later = z/fc
    float* adjf  = (float*)(smem + OFF_ADJ);   // also softmax scratch [8][64]
    float* ss    = (float*)(smem + OFF_SS);    // scores [25][64]
    float (*s_wred)[13][2] = (float(*)[13][2])(smem + OFF_WRED);
    float* s_mu  = (float*)(smem + OFF_MU);
    float* s_rsd = (float*)(smem + OFF_RSD);

    const int bt = blockIdx.x;
    const int tid = threadIdx.x;
    const int d = tid & 255, rep = tid >> 8;
    const int lane = tid & 63, wid = tid >> 6;          // wave id 0-7
    const int lm = lane & 15, quad = lane >> 4;
    const int g0 = rep ? 13 : 0, gn = rep ? 12 : 13;
    const long base = (long)bt * (NG * ND);

    // ---- fragment load helpers ----
    auto loadA = [&](int k0, bf16x8 (&ah)[2], bf16x8 (&al)[2]) {
        const int koff = k0 + quad * 8;
        #pragma unroll
        for (int mt = 0; mt < 2; ++mt) {
            const int off = (mt * 16 + lm) * SB + koff;
            ah[mt] = ld_bf8(hs_hi + off);
            al[mt] = ld_bf8(hs_lo + off);
        }
    };
    auto loadB_qkv = [&](int k0, bf16x8 (&bh)[6], bf16x8 (&bl)[6]) {
        const int koff = k0 + quad * 8;
        #pragma unroll
        for (int j = 0; j < 6; ++j) {
            const int n0 = wid * 96 + j * 16;
            const int mat = n0 >> 8;
            const float* Wf = (mat == 0) ? Wq : (mat == 1 ? Wk : Wv);
            load_bfrag<PREP>(ws + WS_QKV_HI, ws + WS_QKV_LO, Wf,
                             PREP ? (n0 + lm) : ((n0 & 255) + lm), koff, bh[j], bl[j]);
        }
    };
    auto loadB_wo = [&](int k0, bf16x8 (&bh)[2], bf16x8 (&bl)[2]) {
        const int koff = k0 + quad * 8;
        #pragma unroll
        for (int j = 0; j < 2; ++j)
            load_bfrag<PREP>(ws + WS_WO_HI, ws + WS_WO_LO, Wo,
                             wid * 32 + j * 16 + lm, koff, bh[j], bl[j]);
    };
    auto loadB_wfc = [&](int k0, bf16x8 (&bh)[2], bf16x8 (&bl)[2]) {
        const int koff = k0 + quad * 8;
        #pragma unroll
        for (int j = 0; j < 2; ++j)
            load_bfrag<PREP>(ws + WS_WFC_HI, ws + WS_WFC_LO, Wfc,
                             wid * 32 + j * 16 + lm, koff, bh[j], bl[j]);
    };

    // double-buffer fragment registers (slot0 preloaded before each GEMM's barrier)
    bf16x8 bh2[2][6], bl2[2][6];     // QKV
    bf16x8 bh6[2][2], bl6[2][2];     // Wo
    bf16x8 bh8[2][2], bl8[2][2];     // Wfc
    float zx[13];                    // this thread's x residual rows
    float zv[13];                    // z / x1 rows

    // ---- P0: stage adjacency; prefetch alpha/beta ----
    for (int i = tid; i < NG * NG; i += NTH) adjf[i] = adj[i];
    const float af = alpha[d], bef = beta[d];
    __syncthreads();

    // ---- P1: h = adj @ x (VALU, f32), write split-bf16; stash x residual ----
    {
        float acc[13];
        #pragma unroll
        for (int i = 0; i < 13; ++i) acc[i] = 0.f;
        #pragma unroll
        for (int n = 0; n < NG; ++n) {
            float xv = x[base + n * ND + d];
            if (rep == 0) { if (n < 13) zx[n] = xv; }
            else          { if (n >= 13) zx[n - 13] = xv; }
            #pragma unroll
            for (int i = 0; i < 13; ++i)
                acc[i] += adjf[(g0 + i) * NG + n] * xv;   // i==12,rep1 reads in-bounds pad; never stored
        }
        #pragma unroll
        for (int i = 0; i < 13; ++i) {
            if (i >= gn) break;
            u16 h, l; splitf(acc[i], h, l);
            hs_hi[(g0 + i) * SB + d] = h; hs_lo[(g0 + i) * SB + d] = l;
        }
        if (rep) {
            #pragma unroll
            for (int g = NG; g < 32; ++g) { hs_hi[g * SB + d] = 0; hs_lo[g * SB + d] = 0; }
        }
    }
    loadB_qkv(0, bh2[0], bl2[0]);    // prefetch QKV k=0 B-frags across the barrier
    __syncthreads();

    // ---- P2: QKV GEMM (MFMA), double-buffered. C[32,768]; wave wid: cols [wid*96,+96) ----
    {
        float bb[6];
        #pragma unroll
        for (int nt = 0; nt < 6; ++nt) {
            const int n0 = wid * 96 + nt * 16;
            const int mat = n0 >> 8, cb = (n0 & 255) + lm;
            const float* bp = (mat == 0) ? bq : (mat == 1 ? bk : bv);
            bb[nt] = bp[cb];
        }
        f32x4 acc[2][6];
        #pragma unroll
        for (int mt = 0; mt < 2; ++mt)
            #pragma unroll
            for (int nt = 0; nt < 6; ++nt) acc[mt][nt] = (f32x4)0.f;

        bf16x8 ah[2][2], al[2][2];
        loadA(0, ah[0], al[0]);
        #pragma unroll
        for (int ki = 0; ki < 8; ++ki) {
            const int cur = ki & 1, nxt = cur ^ 1;
            if (ki < 7) {
                loadB_qkv(32 * (ki + 1), bh2[nxt], bl2[nxt]);
                loadA(32 * (ki + 1), ah[nxt], al[nxt]);
            }
            #pragma unroll
            for (int j = 0; j < 6; ++j)
                #pragma unroll
                for (int mt = 0; mt < 2; ++mt)
                    acc[mt][j] = __builtin_amdgcn_mfma_f32_16x16x32_bf16(ah[cur][mt], bh2[cur][j], acc[mt][j], 0, 0, 0);
            #pragma unroll
            for (int j = 0; j < 6; ++j)
                #pragma unroll
                for (int mt = 0; mt < 2; ++mt)
                    acc[mt][j] = __builtin_amdgcn_mfma_f32_16x16x32_bf16(al[cur][mt], bh2[cur][j], acc[mt][j], 0, 0, 0);
            #pragma unroll
            for (int j = 0; j < 6; ++j)
                #pragma unroll
                for (int mt = 0; mt < 2; ++mt)
                    acc[mt][j] = __builtin_amdgcn_mfma_f32_16x16x32_bf16(ah[cur][mt], bl2[cur][j], acc[mt][j], 0, 0, 0);
        }
        #pragma unroll
        for (int nt = 0; nt < 6; ++nt) {
            const int n0 = wid * 96 + nt * 16;
            const int mat = n0 >> 8, cb = (n0 & 255) + lm;
            float* plane = qkvf + mat * (32 * SF);
            #pragma unroll
            for (int mt = 0; mt < 2; ++mt)
                #pragma unroll
                for (int i = 0; i < 4; ++i)
                    plane[(mt * 16 + quad * 4 + i) * SF + cb] = acc[mt][nt][i] + bb[nt];
        }
    }
    __syncthreads();

    // ---- P3: scores[g][h1][h2] = Q_g K_g^T / sqrt(32)  (f32) ----
    for (int i = tid; i < NG * 64; i += NTH) {
        const int g = i >> 6, hh = i & 63;
        const float4* q4 = (const float4*)(qkvf + 0 * 32 * SF + g * SF + (hh >> 3) * NHD);
        const float4* k4 = (const float4*)(qkvf + 1 * 32 * SF + g * SF + (hh & 7) * NHD);
        float s = 0.f;
        #pragma unroll
        for (int c = 0; c < 8; ++c) {
            float4 qa = q4[c], ka = k4[c];
            s += qa.x * ka.x + qa.y * ka.y + qa.z * ka.z + qa.w * ka.w;
        }
        ss[i] = s * 0.17677669529663687f;
    }
    __syncthreads();

    // ---- P4: softmax over g (dim=1), 8-way parallel over g-partitions ----
    {
        float* s_sm = adjf;                       // [8][64] scratch (adjf dead)
        const int col = tid & 63, part = tid >> 6;
        float m = -1e30f;
        for (int g = part; g < NG; g += 8) m = fmaxf(m, ss[g * 64 + col]);
        s_sm[part * 64 + col] = m;
        __syncthreads();
        float cm = -1e30f;
        #pragma unroll
        for (int p = 0; p < 8; ++p) cm = fmaxf(cm, s_sm[p * 64 + col]);
        __syncthreads();                          // all reads done before overwrite
        float den = 0.f;
        for (int g = part; g < NG; g += 8) {
            float e = expf(ss[g * 64 + col] - cm);
            ss[g * 64 + col] = e;
            den += e;
        }
        s_sm[part * 64 + col] = den;
        __syncthreads();
        float tden = 0.f;
        #pragma unroll
        for (int p = 0; p < 8; ++p) tden += s_sm[p * 64 + col];
        const float inv = 1.f / tden;
        for (int g = part; g < NG; g += 8) ss[g * 64 + col] *= inv;
    }
    __syncthreads();

    // ---- P5: att = w @ V (f32), write split-bf16 into hs (pad rows still 0) ----
    {
        const int h1 = (tid >> 5) & 7, hd = tid & 31;   // col = d
        const float* Vp = qkvf + 2 * 32 * SF;
        #pragma unroll
        for (int i = 0; i < 13; ++i) {
            if (i >= gn) break;
            const int g = g0 + i;
            float a = 0.f;
            #pragma unroll
            for (int h2 = 0; h2 < NH; ++h2)
                a += ss[g * 64 + h1 * 8 + h2] * Vp[g * SF + h2 * NHD + hd];
            u16 h, l; splitf(a, h, l);
            hs_hi[g * SB + d] = h; hs_lo[g * SB + d] = l;
        }
    }
    loadB_wo(0, bh6[0], bl6[0]);     // prefetch Wo k=0 B-frags across the barrier
    __syncthreads();

    // ---- P6: Wo GEMM (MFMA), double-buffered. C[32,256]; wave wid: cols [wid*32,+32) ----
    {
        float bb[2] = { bo[wid * 32 + lm], bo[wid * 32 + 16 + lm] };
        f32x4 acc[2][2];
        #pragma unroll
        for (int mt = 0; mt < 2; ++mt)
            #pragma unroll
            for (int nt = 0; nt < 2; ++nt) acc[mt][nt] = (f32x4)0.f;

        bf16x8 ah[2][2], al[2][2];
        loadA(0, ah[0], al[0]);
        #pragma unroll
        for (int ki = 0; ki < 8; ++ki) {
            const int cur = ki & 1, nxt = cur ^ 1;
            if (ki < 7) {
                loadB_wo(32 * (ki + 1), bh6[nxt], bl6[nxt]);
                loadA(32 * (ki + 1), ah[nxt], al[nxt]);
            }
            #pragma unroll
            for (int j = 0; j < 2; ++j)
                #pragma unroll
                for (int mt = 0; mt < 2; ++mt)
                    acc[mt][j] = __builtin_amdgcn_mfma_f32_16x16x32_bf16(ah[cur][mt], bh6[cur][j], acc[mt][j], 0, 0, 0);
            #pragma unroll
            for (int j = 0; j < 2; ++j)
                #pragma unroll
                for (int mt = 0; mt < 2; ++mt)
                    acc[mt][j] = __builtin_amdgcn_mfma_f32_16x16x32_bf16(al[cur][mt], bh6[cur][j], acc[mt][j], 0, 0, 0);
            #pragma unroll
            for (int j = 0; j < 2; ++j)
                #pragma unroll
                for (int mt = 0; mt < 2; ++mt)
                    acc[mt][j] = __builtin_amdgcn_mfma_f32_16x16x32_bf16(ah[cur][mt], bl6[cur][j], acc[mt][j], 0, 0, 0);
        }
        float* zs = qkvf;   // plane 0 (Q dead)
        #pragma unroll
        for (int nt = 0; nt < 2; ++nt) {
            const int col = wid * 32 + nt * 16 + lm;
            #pragma unroll
            for (int mt = 0; mt < 2; ++mt)
                #pragma unroll
                for (int i = 0; i < 4; ++i)
                    zs[(mt * 16 + quad * 4 + i) * SF + col] = acc[mt][nt][i] + bb[nt];
        }
    }
    __syncthreads();

    // ---- P7: norm1; x residual from regs; write x1 split-bf16 into hs ----
    {
        float* zs = qkvf;
        #pragma unroll
        for (int i = 0; i < 13; ++i) {
            if (i >= gn) break;
            zv[i] = zs[(g0 + i) * SF + d] + zx[i];
        }
    }
    norm_stats8(zv, gn, lane, wid, tid, s_wred, s_mu, s_rsd);
    #pragma unroll
    for (int i = 0; i < 13; ++i) {
        if (i >= gn) break;
        const float x1 = af * (zv[i] - s_mu[g0 + i]) * s_rsd[g0 + i] + bef;
        zv[i] = x1;
        u16 h, l; splitf(x1, h, l);
        hs_hi[(g0 + i) * SB + d] = h; hs_lo[(g0 + i) * SB + d] = l;
    }
    loadB_wfc(0, bh8[0], bl8[0]);    // prefetch Wfc k=0 B-frags across the barrier
    __syncthreads();

    // ---- P8: Wfc GEMM (MFMA), double-buffered; epilogue relu(acc+bfc) -> zs ----
    {
        float bb[2] = { bfc[wid * 32 + lm], bfc[wid * 32 + 16 + lm] };
        f32x4 acc[2][2];
        #pragma unroll
        for (int mt = 0; mt < 2; ++mt)
            #pragma unroll
            for (int nt = 0; nt < 2; ++nt) acc[mt][nt] = (f32x4)0.f;

        bf16x8 ah[2][2], al[2][2];
        loadA(0, ah[0], al[0]);
        #pragma unroll
        for (int ki = 0; ki < 8; ++ki) {
            const int cur = ki & 1, nxt = cur ^ 1;
            if (ki < 7) {
                loadB_wfc(32 * (ki + 1), bh8[nxt], bl8[nxt]);
                loadA(32 * (ki + 1), ah[nxt], al[nxt]);
            }
            #pragma unroll
            for (int j = 0; j < 2; ++j)
                #pragma unroll
                for (int mt = 0; mt < 2; ++mt)
                    acc[mt][j] = __builtin_amdgcn_mfma_f32_16x16x32_bf16(ah[cur][mt], bh8[cur][j], acc[mt][j], 0, 0, 0);
            #pragma unroll
            for (int j = 0; j < 2; ++j)
                #pragma unroll
                for (int mt = 0; mt < 2; ++mt)
                    acc[mt][j] = __builtin_amdgcn_mfma_f32_16x16x32_bf16(al[cur][mt], bh8[cur][j], acc[mt][j], 0, 0, 0);
            #pragma unroll
            for (int j = 0; j < 2; ++j)
                #pragma unroll
                for (int mt = 0; mt < 2; ++mt)
                    acc[mt][j] = __builtin_amdgcn_mfma_f32_16x16x32_bf16(ah[cur][mt], bl8[cur][j], acc[mt][j], 0, 0, 0);
        }
        float* zs = qkvf;
        #pragma unroll
        for (int nt = 0; nt < 2; ++nt) {
            const int col = wid * 32 + nt * 16 + lm;
            #pragma unroll
            for (int mt = 0; mt < 2; ++mt)
                #pragma unroll
                for (int i = 0; i < 4; ++i)
                    zs[(mt * 16 + quad * 4 + i) * SF + col] = fmaxf(acc[mt][nt][i] + bb[nt], 0.f);
        }
    }
    __syncthreads();

    // ---- P9: norm2 -> out ----
    float z2[13];
    {
        float* zs = qkvf;
        #pragma unroll
        for (int i = 0; i < 13; ++i) {
            if (i >= gn) break;
            z2[i] = zv[i] + zs[(g0 + i) * SF + d];
        }
    }
    norm_stats8(z2, gn, lane, wid, tid, s_wred, s_mu, s_rsd);
    #pragma unroll
    for (int i = 0; i < 13; ++i) {
        if (i >= gn) break;
        out[base + (g0 + i) * ND + d] = af * (z2[i] - s_mu[g0 + i]) * s_rsd[g0 + i] + bef;
    }
}

extern "C" void kernel_launch(void* const* d_in, const int* in_sizes, int n_in,
                              void* d_out, int out_size, void* d_ws, size_t ws_size,
                              hipStream_t stream) {
    (void)in_sizes; (void)n_in; (void)out_size;
    const float* x     = (const float*)d_in[0];
    const float* adj   = (const float*)d_in[1];
    const float* Wq    = (const float*)d_in[2];
    const float* bq    = (const float*)d_in[3];
    const float* Wk    = (const float*)d_in[4];
    const float* bk    = (const float*)d_in[5];
    const float* Wv    = (const float*)d_in[6];
    const float* bv    = (const float*)d_in[7];
    const float* Wo    = (const float*)d_in[8];
    const float* bo    = (const float*)d_in[9];
    const float* Wfc   = (const float*)d_in[10];
    const float* bfc   = (const float*)d_in[11];
    const float* alpha = (const float*)d_in[12];
    const float* beta  = (const float*)d_in[13];
    float* out = (float*)d_out;
    u16* ws = (u16*)d_ws;

    const bool prep = (ws_size >= WS_NEED_BYTES);

    hipFuncSetAttribute((const void*)enc_mfma<true>,
                        hipFuncAttributeMaxDynamicSharedMemorySize, SMEM_TOT);
    hipFuncSetAttribute((const void*)enc_mfma<false>,
                        hipFuncAttributeMaxDynamicSharedMemorySize, SMEM_TOT);

    if (prep) {
        prep_w<<<dim3(1280), dim3(256), 0, stream>>>(Wq, Wk, Wv, Wo, Wfc, ws);
        enc_mfma<true><<<dim3(NB * NT), dim3(NTH), SMEM_TOT, stream>>>(
            x, adj, Wq, bq, Wk, bk, Wv, bv, Wo, bo, Wfc, bfc, alpha, beta, out, ws);
    } else {
        enc_mfma<false><<<dim3(NB * NT), dim3(NTH), SMEM_TOT, stream>>>(
            x, adj, Wq, bq, Wk, bk, Wv, bv, Wo, bo, Wfc, bfc, alpha, beta, out, ws);
    }
}